// Round 8
// baseline (403.865 us; speedup 1.0000x reference)
//
#include <hip/hip_runtime.h>
#include <hip/hip_bf16.h>
#include <cstddef>

#define CH 128
#define BN_EPS 1e-5f
#define STATS_BLOCKS 2048
#define FOLD_BLOCKS 256
#define STATS2_GRID 2048

typedef __bf16 bf16x8 __attribute__((ext_vector_type(8)));
typedef __bf16 bf16x4 __attribute__((ext_vector_type(4)));
typedef float  f32x4  __attribute__((ext_vector_type(4)));

__device__ inline float bf2f(__bf16 b) { return (float)b; }

__device__ inline f32x4 nt_load4(const float* p) {
    return __builtin_nontemporal_load((const f32x4*)p);
}
__device__ inline void nt_store4(float* p, f32x4 v) {
    __builtin_nontemporal_store(v, (f32x4*)p);
}

// ---------------------------------------------------------------------------
// R14 == R13 resubmitted (R13 bench failed at container level, not kernel).
// Theory: four structurally different agg variants all converge to ~52us at
// ~4TB/s -> pattern BW ceiling. Lever = fewer bytes in the gather kernel:
// stage-2 reorder  A-hat(H W2'^T + 1 bias'^T) = (A-hat H) W2'^T + s bias'^T
// with s[i] = rowsum(A-hat) (computed in agg1 from norms it already loads).
// agg2' gathers h2raw -> aggH bf16 (25.6MB write, no x read); gemm2'' does
// the full epilogue (s*bias' + b2, relu, +x, f32 out) at streaming BW.
// stats2 fused as agg2' tail blocks (both read h2raw) -> 9 dispatches.
// slot[] dropped: count = fire-and-forget atomics; fill claims via
// atomicAdd on cur[] (copy of offs written by scan).
// ---------------------------------------------------------------------------

// ---- K1: count (4 edges/thread, no return) + stats1 over x + wprep W1 ------
__global__ __launch_bounds__(256) void k1_kernel(
    const int* __restrict__ dst, int* __restrict__ cnt, int E,
    const float* __restrict__ x, float* __restrict__ partials, int total4,
    const float* __restrict__ W1, __bf16* __restrict__ W1b,
    int NB_COUNT4, int NB_STATS) {
    int b = blockIdx.x;
    if (b < NB_COUNT4) {
        int base = b * 1024 + threadIdx.x;
        #pragma unroll
        for (int j = 0; j < 4; ++j) {
            int e = base + j * 256;
            if (e < E) atomicAdd(&cnt[dst[e]], 1);
        }
    } else if (b < NB_COUNT4 + NB_STATS) {
        // per-channel sum & sumsq -> per-block partial row (sums||sumsq)
        int sbid = b - NB_COUNT4;
        int l = threadIdx.x & 31;
        int g = threadIdx.x >> 5;
        float4 s  = make_float4(0.f, 0.f, 0.f, 0.f);
        float4 s2 = make_float4(0.f, 0.f, 0.f, 0.f);
        int gid = sbid * 256 + threadIdx.x;
        int gs = NB_STATS * 256;
        const float4* in4 = (const float4*)x;

        auto accum = [&](float4 v) {
            s.x += v.x; s.y += v.y; s.z += v.z; s.w += v.w;
            s2.x += v.x * v.x; s2.y += v.y * v.y; s2.z += v.z * v.z; s2.w += v.w * v.w;
        };

        int i = gid;
        for (; i + 3 * gs < total4; i += 4 * gs) {
            float4 v0 = in4[i];
            float4 v1 = in4[i + gs];
            float4 v2 = in4[i + 2 * gs];
            float4 v3 = in4[i + 3 * gs];
            accum(v0); accum(v1); accum(v2); accum(v3);
        }
        for (; i < total4; i += gs) accum(in4[i]);

        __shared__ float4 ls[8][32], ls2[8][32];
        ls[g][l] = s; ls2[g][l] = s2;
        __syncthreads();
        if (g == 0) {
            #pragma unroll
            for (int k = 1; k < 8; ++k) {
                float4 a = ls[k][l], bb = ls2[k][l];
                s.x += a.x; s.y += a.y; s.z += a.z; s.w += a.w;
                s2.x += bb.x; s2.y += bb.y; s2.z += bb.z; s2.w += bb.w;
            }
            ((float4*)partials)[sbid * 64 + l]      = s;
            ((float4*)partials)[sbid * 64 + 32 + l] = s2;
        }
    } else {
        int i = (b - NB_COUNT4 - NB_STATS) * 256 + threadIdx.x;
        if (i < CH * CH) W1b[i] = (__bf16)W1[i];
    }
}

// ---- reduce partial rows + BN params (8 channels per block) ----------------
__device__ inline void reducebn_body(
    int blk, const float* __restrict__ partials, int R,
    const float* __restrict__ gamma, const float* __restrict__ beta,
    float* __restrict__ scale, float* __restrict__ shift, float inv_n) {
    __shared__ float l1[256], l2[256];
    int t = threadIdx.x;
    int cl = t & 7;
    int r0 = t >> 3;
    int c = blk * 8 + cl;
    float a1 = 0.f, a2 = 0.f;
    for (int r = r0; r < R; r += 32) {
        a1 += partials[(size_t)r * 256 + c];
        a2 += partials[(size_t)r * 256 + 128 + c];
    }
    l1[t] = a1; l2[t] = a2;
    __syncthreads();
    #pragma unroll
    for (int off = 16; off >= 1; off >>= 1) {
        if (r0 < off) {
            l1[t] += l1[t + off * 8];
            l2[t] += l2[t + off * 8];
        }
        __syncthreads();
    }
    if (t < 8) {
        float mean = l1[t] * inv_n;
        float var  = l2[t] * inv_n - mean * mean;  // biased
        float sc = gamma[c] * rsqrtf(var + BN_EPS);
        scale[c] = sc;
        shift[c] = beta[c] - mean * sc;
    }
}

// ---- K2: atomic-base scan (writes offs + cur) + dinv + fold1 ---------------
__global__ __launch_bounds__(256) void k2_kernel(
    const int* __restrict__ cnt, int* __restrict__ offs, int* __restrict__ cur,
    int* __restrict__ cursor, float* __restrict__ dinv, int n,
    const float* __restrict__ partials, float* __restrict__ p2a,
    int NB_SCAN, int NB_DINV) {
    int b = blockIdx.x;
    int t = threadIdx.x;
    if (b < NB_SCAN) {
        __shared__ int sd[256];
        __shared__ int sbase;
        int base = b * 1024 + t * 4;
        int v[4];
        #pragma unroll
        for (int j = 0; j < 4; ++j) v[j] = (base + j < n) ? cnt[base + j] : 0;
        int s = v[0] + v[1] + v[2] + v[3];
        sd[t] = s;
        __syncthreads();
        for (int off = 1; off < 256; off <<= 1) {
            int xv = (t >= off) ? sd[t - off] : 0;
            __syncthreads();
            sd[t] += xv;
            __syncthreads();
        }
        if (t == 255) sbase = atomicAdd(cursor, sd[255]);
        __syncthreads();
        int run = sbase + sd[t] - s;
        #pragma unroll
        for (int j = 0; j < 4; ++j) {
            if (base + j < n) { offs[base + j] = run; cur[base + j] = run; }
            run += v[j];
        }
    } else if (b < NB_SCAN + NB_DINV) {
        int ib = (b - NB_SCAN) * 1024 + t * 4;
        #pragma unroll
        for (int j = 0; j < 4; ++j) {
            int i = ib + j;
            if (i < n) dinv[i] = rsqrtf((float)cnt[i] + 1.0f);  // +1 self loop
        }
    } else {
        // fold1: STATS_BLOCKS partial rows -> FOLD_BLOCKS rows
        int fb = b - NB_SCAN - NB_DINV;
        float acc = 0.f;
        for (int r = fb; r < STATS_BLOCKS; r += FOLD_BLOCKS)
            acc += partials[(size_t)r * 256 + t];
        p2a[(size_t)fb * 256 + t] = acc;
    }
}

// ---- fill CSR (4 edges/thread, atomic cursor) + reducebn1 tail blocks ------
__global__ __launch_bounds__(256) void fill_kernel(
    const int* __restrict__ src, const int* __restrict__ dst,
    int* __restrict__ cur, const float* __restrict__ dinv,
    int2* __restrict__ csr, int E,
    const float* __restrict__ p2a,
    const float* __restrict__ gamma1, const float* __restrict__ beta1,
    float* __restrict__ scale1, float* __restrict__ shift1, int n,
    int NB_FILL4) {
    int b = blockIdx.x;
    if (b < NB_FILL4) {
        int base = b * 1024 + threadIdx.x;
        #pragma unroll
        for (int j = 0; j < 4; ++j) {
            int e = base + j * 256;
            if (e < E) {
                int s = src[e], d = dst[e];
                int p = atomicAdd(&cur[d], 1);
                float nrm = dinv[s] * dinv[d];
                csr[p] = make_int2(s, __float_as_int(nrm));
            }
        }
    } else {
        reducebn_body(b - NB_FILL4, p2a, FOLD_BLOCKS, gamma1, beta1,
                      scale1, shift1, 1.0f / (float)n);
    }
}

// ---- reducebn2 + W2' prep + bias' partials (16 blocks, 8 channels each) ----
__global__ __launch_bounds__(256) void rbn2w2_kernel(
    const float* __restrict__ p2b,
    const float* __restrict__ gamma, const float* __restrict__ beta,
    const float* __restrict__ W2, __bf16* __restrict__ W2b,
    float* __restrict__ bias2p, int n) {
    __shared__ float l1[256], l2[256];
    __shared__ float ssc[8], ssh[8];
    int t = threadIdx.x;
    int blk = blockIdx.x;
    int cl = t & 7;
    int r0 = t >> 3;
    int c = blk * 8 + cl;
    float a1 = 0.f, a2 = 0.f;
    for (int r = r0; r < FOLD_BLOCKS; r += 32) {
        a1 += p2b[(size_t)r * 256 + c];
        a2 += p2b[(size_t)r * 256 + 128 + c];
    }
    l1[t] = a1; l2[t] = a2;
    __syncthreads();
    #pragma unroll
    for (int off = 16; off >= 1; off >>= 1) {
        if (r0 < off) {
            l1[t] += l1[t + off * 8];
            l2[t] += l2[t + off * 8];
        }
        __syncthreads();
    }
    if (t < 8) {
        int cc = blk * 8 + t;
        float inv_n = 1.0f / (float)n;
        float mean = l1[t] * inv_n;
        float var  = l2[t] * inv_n - mean * mean;
        float sc = gamma[cc] * rsqrtf(var + BN_EPS);
        float sh = beta[cc] - mean * sc;
        ssc[t] = sc;
        ssh[t] = sh;
    }
    __syncthreads();
    // W2' columns blk*8 .. blk*8+7 : W2'[j][k] = W2[j][k] * scale2[k]
    for (int idx = t; idx < 128 * 8; idx += 256) {
        int j = idx >> 3, kk = idx & 7;
        int k = blk * 8 + kk;
        W2b[j * CH + k] = (__bf16)(W2[j * CH + k] * ssc[kk]);
    }
    // bias' partial: bias2p[j] += sum_kk shift2[k] * W2[j][k]
    if (t < CH) {
        float acc = 0.f;
        #pragma unroll
        for (int kk = 0; kk < 8; ++kk)
            acc += ssh[kk] * W2[t * CH + blk * 8 + kk];
        atomicAdd(&bias2p[t], acc);
    }
}

// ---- MFMA GEMM 1: f32 A with BN1 transform ---------------------------------
#define GROWS 64
#define LDA 136

__global__ __launch_bounds__(256) void gemm_kernel(
    const float* __restrict__ A,
    const float* __restrict__ scale, const float* __restrict__ shift,
    const __bf16* __restrict__ Wb, __bf16* __restrict__ Hout, int n) {
    __shared__ __bf16 As[GROWS][LDA];
    int tid = threadIdx.x;
    int row0 = blockIdx.x * GROWS;

    #pragma unroll
    for (int p = 0; p < 8; ++p) {
        int idx = p * 256 + tid;
        int r = idx >> 5;
        int f4 = idx & 31;
        int c4 = f4 * 4;
        int row = row0 + r;
        f32x4 v = {0.f, 0.f, 0.f, 0.f};
        if (row < n) v = *((const f32x4*)A + ((size_t)row * 32 + f4));
        __bf16 u[4];
        #pragma unroll
        for (int j = 0; j < 4; ++j) {
            int ch = c4 + j;
            u[j] = (__bf16)(v[j] * scale[ch] + shift[ch]);
        }
        *(bf16x4*)&As[r][c4] = *(bf16x4*)u;
    }
    __syncthreads();

    int wv = tid >> 6;
    int lane = tid & 63;
    int m = lane & 15;
    int q = lane >> 4;
    int arow = wv * 16 + m;
    f32x4 acc[8] = {};
    #pragma unroll
    for (int kc = 0; kc < CH; kc += 32) {
        bf16x8 af = *(const bf16x8*)&As[arow][kc + q * 8];
        #pragma unroll
        for (int t = 0; t < 8; ++t) {
            bf16x8 bf = *(const bf16x8*)&Wb[(size_t)(t * 16 + m) * CH + kc + q * 8];
            acc[t] = __builtin_amdgcn_mfma_f32_16x16x32_bf16(af, bf, acc[t], 0, 0, 0);
        }
    }

    #pragma unroll
    for (int t = 0; t < 8; ++t) {
        #pragma unroll
        for (int r = 0; r < 4; ++r) {
            int row = row0 + wv * 16 + q * 4 + r;
            if (row < n) Hout[(size_t)row * CH + t * 16 + m] = (__bf16)acc[t][r];
        }
    }
}

// ---- MFMA GEMM 2'': aggH bf16 @ W2'^T + s*bias' + b2, relu, +x -> out f32 --
__global__ __launch_bounds__(256) void gemm2_kernel(
    const __bf16* __restrict__ A, const __bf16* __restrict__ Wb,
    const float* __restrict__ bias2p, const float* __restrict__ s_arr,
    const float* __restrict__ b2, const float* __restrict__ x,
    float* __restrict__ out, int n) {
    __shared__ __bf16 As[GROWS][LDA];
    int tid = threadIdx.x;
    int row0 = blockIdx.x * GROWS;

    #pragma unroll
    for (int p = 0; p < 4; ++p) {
        int idx = p * 256 + tid;
        int r = idx >> 4;          // 64 rows, 16 slots of bf16x8
        int f8 = idx & 15;
        int c8 = f8 * 8;
        int row = row0 + r;
        bf16x8 v = {};
        if (row < n) v = *(const bf16x8*)&A[(size_t)row * CH + c8];
        *(bf16x8*)&As[r][c8] = v;
    }
    __syncthreads();

    int wv = tid >> 6;
    int lane = tid & 63;
    int m = lane & 15;
    int q = lane >> 4;
    int arow = wv * 16 + m;
    f32x4 acc[8] = {};
    #pragma unroll
    for (int kc = 0; kc < CH; kc += 32) {
        bf16x8 af = *(const bf16x8*)&As[arow][kc + q * 8];
        #pragma unroll
        for (int t = 0; t < 8; ++t) {
            bf16x8 bf = *(const bf16x8*)&Wb[(size_t)(t * 16 + m) * CH + kc + q * 8];
            acc[t] = __builtin_amdgcn_mfma_f32_16x16x32_bf16(af, bf, acc[t], 0, 0, 0);
        }
    }

    float sv[4];
    #pragma unroll
    for (int r = 0; r < 4; ++r) {
        int row = row0 + wv * 16 + q * 4 + r;
        sv[r] = (row < n) ? s_arr[row] : 0.f;
    }
    #pragma unroll
    for (int t = 0; t < 8; ++t) {
        int col = t * 16 + m;
        float bp = bias2p[col];
        float bb = b2[col];
        #pragma unroll
        for (int r = 0; r < 4; ++r) {
            int row = row0 + wv * 16 + q * 4 + r;
            if (row < n) {
                float v = fmaxf(acc[t][r] + sv[r] * bp + bb, 0.f);
                v += __builtin_nontemporal_load(&x[(size_t)row * CH + col]);
                __builtin_nontemporal_store(v, &out[(size_t)row * CH + col]);
            }
        }
    }
}

// ---------------------------------------------------------------------------
// Gather core with batched pointer loads: lane (tid&15) fetches csr[e+lane]
// (one coalesced 128B load = up to 16 edge pointers per node-group), pointers
// distributed via __shfl. Returns sum of norms (for s[] = rowsum(A-hat)).
// ---------------------------------------------------------------------------
__device__ inline float agg_core(
    const __bf16* __restrict__ h, const int2* __restrict__ csr,
    const int* __restrict__ offs, const int* __restrict__ cnt,
    const float* __restrict__ dinv, int node, int c, float a[8]) {
    float di = dinv[node];
    float w0 = di * di;
    bf16x8 hv = *(const bf16x8*)&h[(size_t)node * CH + c];
    #pragma unroll
    for (int j = 0; j < 8; ++j) a[j] = bf2f(hv[j]) * w0;

    int e = offs[node];
    int end = e + cnt[node];
    int gl = threadIdx.x & 48;   // group base lane within wave
    int il = threadIdx.x & 15;   // lane within group
    float sn = 0.f;

    while (e < end) {
        int take = end - e;
        if (take > 16) take = 16;
        int2 pe = csr[e + (il < take ? il : take - 1)];
        int j = 0;
        for (; j + 4 <= take; j += 4) {
            int s0 = __shfl(pe.x, gl + j);
            int s1 = __shfl(pe.x, gl + j + 1);
            int s2 = __shfl(pe.x, gl + j + 2);
            int s3 = __shfl(pe.x, gl + j + 3);
            float n0 = __int_as_float(__shfl(pe.y, gl + j));
            float n1 = __int_as_float(__shfl(pe.y, gl + j + 1));
            float n2 = __int_as_float(__shfl(pe.y, gl + j + 2));
            float n3 = __int_as_float(__shfl(pe.y, gl + j + 3));
            bf16x8 v0 = *(const bf16x8*)&h[(size_t)s0 * CH + c];
            bf16x8 v1 = *(const bf16x8*)&h[(size_t)s1 * CH + c];
            bf16x8 v2 = *(const bf16x8*)&h[(size_t)s2 * CH + c];
            bf16x8 v3 = *(const bf16x8*)&h[(size_t)s3 * CH + c];
            sn += n0 + n1 + n2 + n3;
            #pragma unroll
            for (int k = 0; k < 8; ++k) {
                a[k] += bf2f(v0[k]) * n0;
                a[k] += bf2f(v1[k]) * n1;
                a[k] += bf2f(v2[k]) * n2;
                a[k] += bf2f(v3[k]) * n3;
            }
        }
        for (; j < take; ++j) {
            int s0 = __shfl(pe.x, gl + j);
            float n0 = __int_as_float(__shfl(pe.y, gl + j));
            bf16x8 v0 = *(const bf16x8*)&h[(size_t)s0 * CH + c];
            sn += n0;
            #pragma unroll
            for (int k = 0; k < 8; ++k) a[k] += bf2f(v0[k]) * n0;
        }
        e += take;
    }
    return sn;
}

// agg1: relu(a + b1) -> bf16 h2raw + s[] = rowsum(A-hat)
__global__ __launch_bounds__(256) void agg1_kernel(
    const __bf16* __restrict__ h, const int2* __restrict__ csr,
    const int* __restrict__ offs, const int* __restrict__ cnt,
    const float* __restrict__ dinv, const float* __restrict__ b1,
    __bf16* __restrict__ h2raw, float* __restrict__ s_arr, int n) {
    int tid = threadIdx.x;
    int node = blockIdx.x * 16 + (tid >> 4);
    if (node >= n) return;
    int c = (tid & 15) * 8;
    float a[8];
    float sn = agg_core(h, csr, offs, cnt, dinv, node, c, a);

    if ((tid & 15) == 0) {
        float di = dinv[node];
        s_arr[node] = di * di + sn;
    }

    __bf16 u[8];
    #pragma unroll
    for (int j = 0; j < 8; ++j) u[j] = (__bf16)fmaxf(a[j] + b1[c + j], 0.f);
    *(bf16x8*)&h2raw[(size_t)node * CH + c] = *(bf16x8*)u;
}

// agg2' + fused stats2: leading blocks gather h2raw -> aggH bf16;
// tail blocks stream h2raw -> per-channel sums into p2b (atomicAdd).
__global__ __launch_bounds__(256) void agg2s_kernel(
    const __bf16* __restrict__ h2, const int2* __restrict__ csr,
    const int* __restrict__ offs, const int* __restrict__ cnt,
    const float* __restrict__ dinv, __bf16* __restrict__ aggH,
    float* __restrict__ p2b, int n, int NB_AGG, int total16) {
    int b = blockIdx.x;
    int t = threadIdx.x;
    if (b < NB_AGG) {
        int node = b * 16 + (t >> 4);
        if (node >= n) return;
        int c = (t & 15) * 8;
        float a[8];
        agg_core(h2, csr, offs, cnt, dinv, node, c, a);
        __bf16 u[8];
        #pragma unroll
        for (int j = 0; j < 8; ++j) u[j] = (__bf16)a[j];
        *(bf16x8*)&aggH[(size_t)node * CH + c] = *(bf16x8*)u;
    } else {
        int sbid = b - NB_AGG;
        float s[8] = {}, q[8] = {};
        int gs = STATS2_GRID * 256;
        for (int i = sbid * 256 + t; i < total16; i += gs) {
            bf16x8 v = *(const bf16x8*)&h2[(size_t)i * 8];
            #pragma unroll
            for (int k = 0; k < 8; ++k) {
                float f = bf2f(v[k]);
                s[k] += f;
                q[k] += f * f;
            }
        }
        #pragma unroll
        for (int k = 0; k < 8; ++k) {
            s[k] += __shfl_xor(s[k], 16);
            q[k] += __shfl_xor(q[k], 16);
            s[k] += __shfl_xor(s[k], 32);
            q[k] += __shfl_xor(q[k], 32);
        }
        __shared__ float red[2][4][16][8];
        int w = t >> 6, l = t & 63;
        if (l < 16) {
            #pragma unroll
            for (int k = 0; k < 8; ++k) {
                red[0][w][l][k] = s[k];
                red[1][w][l][k] = q[k];
            }
        }
        __syncthreads();
        int half = t >> 7;
        int rem = t & 127;
        int g = rem >> 3;
        int k = rem & 7;
        float acc = red[half][0][g][k] + red[half][1][g][k]
                  + red[half][2][g][k] + red[half][3][g][k];
        atomicAdd(&p2b[(size_t)(sbid & 255) * 256 + half * 128 + g * 8 + k], acc);
    }
}

extern "C" void kernel_launch(void* const* d_in, const int* in_sizes, int n_in,
                              void* d_out, int out_size, void* d_ws, size_t ws_size,
                              hipStream_t stream) {
    const float* x      = (const float*)d_in[0];
    const int*   eidx   = (const int*)d_in[1];
    const float* W1     = (const float*)d_in[2];
    const float* b1     = (const float*)d_in[3];
    const float* W2     = (const float*)d_in[4];
    const float* b2     = (const float*)d_in[5];
    const float* gamma1 = (const float*)d_in[6];
    const float* beta1  = (const float*)d_in[7];
    const float* gamma2 = (const float*)d_in[8];
    const float* beta2  = (const float*)d_in[9];
    float* out = (float*)d_out;

    const int N = in_sizes[0] / CH;
    const int E = in_sizes[1] / 2;
    const int* src = eidx;
    const int* dst = eidx + E;

    const int NAGG = (N + 15) / 16;

    char* ws = (char*)d_ws;
    size_t off = 0;
    auto carve = [&](size_t bytes) { char* p = ws + off; off = (off + bytes + 1023) & ~(size_t)1023; return p; };
    // ---- zeroed region (one memset): cnt+cursor, bias2p, p2b ----
    int*    cnt      = (int*)carve((size_t)(N + 1) * 4);  // cnt[N] = scan cursor
    float*  bias2p   = (float*)carve(CH * 4);
    float*  p2b      = (float*)carve((size_t)FOLD_BLOCKS * 256 * 4);
    // ---- rest ----
    float*  dinv     = (float*)carve((size_t)N * 4);
    int*    offs     = (int*)carve((size_t)N * 4);
    int*    cur      = (int*)carve((size_t)N * 4);
    float*  s_arr    = (float*)carve((size_t)N * 4);
    float*  small    = (float*)carve(8 * CH * 4);
    float*  p2a      = (float*)carve((size_t)FOLD_BLOCKS * 256 * 4);
    float*  partials = (float*)carve((size_t)STATS_BLOCKS * 256 * 4);
    int2*   csr      = (int2*)carve((size_t)E * 8);
    __bf16* W1b      = (__bf16*)carve((size_t)CH * CH * 2);
    __bf16* W2b      = (__bf16*)carve((size_t)CH * CH * 2);  // holds W2' (prescaled)
    __bf16* h_bf     = (__bf16*)carve((size_t)N * CH * 2);   // gemm1 out; reused as aggH
    __bf16* h2raw    = (__bf16*)carve((size_t)N * CH * 2);   // relu(agg1+b1), bf16
    float* scale1 = small + 4 * CH;
    float* shift1 = small + 5 * CH;
    (void)ws_size; (void)n_in; (void)out_size;

    int* cursor = cnt + N;
    size_t zbytes = (size_t)((char*)p2b - (char*)cnt) + (size_t)FOLD_BLOCKS * 256 * 4;
    hipMemsetAsync(cnt, 0, zbytes, stream);

    const int NB_COUNT4 = (E + 1023) / 1024;
    const int NB_STATS  = STATS_BLOCKS;
    const int NB_WPREP  = (CH * CH + 255) / 256;
    const int NB_SCAN   = (N + 1023) / 1024;
    const int NB_DINV   = (N + 1023) / 1024;
    const int NB_FILL4  = (E + 1023) / 1024;
    const int NB_GEMM   = (N + GROWS - 1) / GROWS;

    // K1: count(4/thread, no-return atomics) + stats1(x)@2048 + W1 bf16 prep
    k1_kernel<<<NB_COUNT4 + NB_STATS + NB_WPREP, 256, 0, stream>>>(
        dst, cnt, E, x, partials, N * 32, W1, W1b, NB_COUNT4, NB_STATS);

    // K2: scan(atomic base; writes offs+cur) + dinv + fold1 (2048->256 rows)
    k2_kernel<<<NB_SCAN + NB_DINV + FOLD_BLOCKS, 256, 0, stream>>>(
        cnt, offs, cur, cursor, dinv, N, partials, p2a, NB_SCAN, NB_DINV);

    // fill CSR (4/thread, atomic cursor) + reducebn1 tail (16 blocks)
    fill_kernel<<<NB_FILL4 + 16, 256, 0, stream>>>(
        src, dst, cur, dinv, csr, E,
        p2a, gamma1, beta1, scale1, shift1, N, NB_FILL4);

    // gemm1: h = BN1(x) @ W1^T  (bf16 out)
    gemm_kernel<<<NB_GEMM, 256, 0, stream>>>(x, scale1, shift1, W1b, h_bf, N);

    // agg1: relu(A-hat h + b1) -> h2raw bf16 + s[] = rowsum(A-hat)
    agg1_kernel<<<NAGG, 256, 0, stream>>>(h_bf, csr, offs, cnt, dinv,
                                          b1, h2raw, s_arr, N);

    // agg2' (gather h2raw -> aggH bf16) + fused stats2 tail blocks
    agg2s_kernel<<<NAGG + STATS2_GRID, 256, 0, stream>>>(
        h2raw, csr, offs, cnt, dinv, h_bf, p2b, N, NAGG, N * 16);

    // reducebn2 + W2' prep + bias' accumulation
    rbn2w2_kernel<<<16, 256, 0, stream>>>(p2b, gamma2, beta2,
                                          W2, W2b, bias2p, N);

    // gemm2'': out = relu(aggH @ W2'^T + s*bias' + b2) + x  (f32, nt)
    gemm2_kernel<<<NB_GEMM, 256, 0, stream>>>(h_bf, W2b, bias2p, s_arr,
                                              b2, x, out, N);
}

// Round 9
// 377.126 us; speedup vs baseline: 1.0709x; 1.0709x over previous
//
#include <hip/hip_runtime.h>
#include <hip/hip_bf16.h>
#include <cstddef>

#define CH 128
#define BN_EPS 1e-5f
#define STATS_BLOCKS 2048
#define FOLD_BLOCKS 256
#define STATS2_GRID 2048

typedef __bf16 bf16x8 __attribute__((ext_vector_type(8)));
typedef __bf16 bf16x4 __attribute__((ext_vector_type(4)));
typedef float  f32x4  __attribute__((ext_vector_type(4)));

__device__ inline float bf2f(__bf16 b) { return (float)b; }

__device__ inline f32x4 nt_load4(const float* p) {
    return __builtin_nontemporal_load((const f32x4*)p);
}
__device__ inline void nt_store4(float* p, f32x4 v) {
    __builtin_nontemporal_store(v, (f32x4*)p);
}

// ---------------------------------------------------------------------------
// R15: R14's gemm2'' ran at 1.5TB/s (76us, occupancy 31%, all pipes idle):
// the MFMA C-layout scattered the epilogue into 64 scalar 4B nt-load/store
// round-trips per thread -- latency-bound. Fix: LDS transpose stage. Dump
// acc into f32 Cs[64][132] (aliases the As staging buffer), sync, then
// vectorized row-major epilogue: coalesced f32x4 x-loads + nt f32x4 stores.
// Same bytes, streaming transactions. Dataflow unchanged from R13/R14.
// ---------------------------------------------------------------------------

// ---- K1: count (4 edges/thread, no return) + stats1 over x + wprep W1 ------
__global__ __launch_bounds__(256) void k1_kernel(
    const int* __restrict__ dst, int* __restrict__ cnt, int E,
    const float* __restrict__ x, float* __restrict__ partials, int total4,
    const float* __restrict__ W1, __bf16* __restrict__ W1b,
    int NB_COUNT4, int NB_STATS) {
    int b = blockIdx.x;
    if (b < NB_COUNT4) {
        int base = b * 1024 + threadIdx.x;
        #pragma unroll
        for (int j = 0; j < 4; ++j) {
            int e = base + j * 256;
            if (e < E) atomicAdd(&cnt[dst[e]], 1);
        }
    } else if (b < NB_COUNT4 + NB_STATS) {
        // per-channel sum & sumsq -> per-block partial row (sums||sumsq)
        int sbid = b - NB_COUNT4;
        int l = threadIdx.x & 31;
        int g = threadIdx.x >> 5;
        float4 s  = make_float4(0.f, 0.f, 0.f, 0.f);
        float4 s2 = make_float4(0.f, 0.f, 0.f, 0.f);
        int gid = sbid * 256 + threadIdx.x;
        int gs = NB_STATS * 256;
        const float4* in4 = (const float4*)x;

        auto accum = [&](float4 v) {
            s.x += v.x; s.y += v.y; s.z += v.z; s.w += v.w;
            s2.x += v.x * v.x; s2.y += v.y * v.y; s2.z += v.z * v.z; s2.w += v.w * v.w;
        };

        int i = gid;
        for (; i + 3 * gs < total4; i += 4 * gs) {
            float4 v0 = in4[i];
            float4 v1 = in4[i + gs];
            float4 v2 = in4[i + 2 * gs];
            float4 v3 = in4[i + 3 * gs];
            accum(v0); accum(v1); accum(v2); accum(v3);
        }
        for (; i < total4; i += gs) accum(in4[i]);

        __shared__ float4 ls[8][32], ls2[8][32];
        ls[g][l] = s; ls2[g][l] = s2;
        __syncthreads();
        if (g == 0) {
            #pragma unroll
            for (int k = 1; k < 8; ++k) {
                float4 a = ls[k][l], bb = ls2[k][l];
                s.x += a.x; s.y += a.y; s.z += a.z; s.w += a.w;
                s2.x += bb.x; s2.y += bb.y; s2.z += bb.z; s2.w += bb.w;
            }
            ((float4*)partials)[sbid * 64 + l]      = s;
            ((float4*)partials)[sbid * 64 + 32 + l] = s2;
        }
    } else {
        int i = (b - NB_COUNT4 - NB_STATS) * 256 + threadIdx.x;
        if (i < CH * CH) W1b[i] = (__bf16)W1[i];
    }
}

// ---- reduce partial rows + BN params (8 channels per block) ----------------
__device__ inline void reducebn_body(
    int blk, const float* __restrict__ partials, int R,
    const float* __restrict__ gamma, const float* __restrict__ beta,
    float* __restrict__ scale, float* __restrict__ shift, float inv_n) {
    __shared__ float l1[256], l2[256];
    int t = threadIdx.x;
    int cl = t & 7;
    int r0 = t >> 3;
    int c = blk * 8 + cl;
    float a1 = 0.f, a2 = 0.f;
    for (int r = r0; r < R; r += 32) {
        a1 += partials[(size_t)r * 256 + c];
        a2 += partials[(size_t)r * 256 + 128 + c];
    }
    l1[t] = a1; l2[t] = a2;
    __syncthreads();
    #pragma unroll
    for (int off = 16; off >= 1; off >>= 1) {
        if (r0 < off) {
            l1[t] += l1[t + off * 8];
            l2[t] += l2[t + off * 8];
        }
        __syncthreads();
    }
    if (t < 8) {
        float mean = l1[t] * inv_n;
        float var  = l2[t] * inv_n - mean * mean;  // biased
        float sc = gamma[c] * rsqrtf(var + BN_EPS);
        scale[c] = sc;
        shift[c] = beta[c] - mean * sc;
    }
}

// ---- K2: atomic-base scan (writes offs + cur) + dinv + fold1 ---------------
__global__ __launch_bounds__(256) void k2_kernel(
    const int* __restrict__ cnt, int* __restrict__ offs, int* __restrict__ cur,
    int* __restrict__ cursor, float* __restrict__ dinv, int n,
    const float* __restrict__ partials, float* __restrict__ p2a,
    int NB_SCAN, int NB_DINV) {
    int b = blockIdx.x;
    int t = threadIdx.x;
    if (b < NB_SCAN) {
        __shared__ int sd[256];
        __shared__ int sbase;
        int base = b * 1024 + t * 4;
        int v[4];
        #pragma unroll
        for (int j = 0; j < 4; ++j) v[j] = (base + j < n) ? cnt[base + j] : 0;
        int s = v[0] + v[1] + v[2] + v[3];
        sd[t] = s;
        __syncthreads();
        for (int off = 1; off < 256; off <<= 1) {
            int xv = (t >= off) ? sd[t - off] : 0;
            __syncthreads();
            sd[t] += xv;
            __syncthreads();
        }
        if (t == 255) sbase = atomicAdd(cursor, sd[255]);
        __syncthreads();
        int run = sbase + sd[t] - s;
        #pragma unroll
        for (int j = 0; j < 4; ++j) {
            if (base + j < n) { offs[base + j] = run; cur[base + j] = run; }
            run += v[j];
        }
    } else if (b < NB_SCAN + NB_DINV) {
        int ib = (b - NB_SCAN) * 1024 + t * 4;
        #pragma unroll
        for (int j = 0; j < 4; ++j) {
            int i = ib + j;
            if (i < n) dinv[i] = rsqrtf((float)cnt[i] + 1.0f);  // +1 self loop
        }
    } else {
        // fold1: STATS_BLOCKS partial rows -> FOLD_BLOCKS rows
        int fb = b - NB_SCAN - NB_DINV;
        float acc = 0.f;
        for (int r = fb; r < STATS_BLOCKS; r += FOLD_BLOCKS)
            acc += partials[(size_t)r * 256 + t];
        p2a[(size_t)fb * 256 + t] = acc;
    }
}

// ---- fill CSR (4 edges/thread, atomic cursor) + reducebn1 tail blocks ------
__global__ __launch_bounds__(256) void fill_kernel(
    const int* __restrict__ src, const int* __restrict__ dst,
    int* __restrict__ cur, const float* __restrict__ dinv,
    int2* __restrict__ csr, int E,
    const float* __restrict__ p2a,
    const float* __restrict__ gamma1, const float* __restrict__ beta1,
    float* __restrict__ scale1, float* __restrict__ shift1, int n,
    int NB_FILL4) {
    int b = blockIdx.x;
    if (b < NB_FILL4) {
        int base = b * 1024 + threadIdx.x;
        #pragma unroll
        for (int j = 0; j < 4; ++j) {
            int e = base + j * 256;
            if (e < E) {
                int s = src[e], d = dst[e];
                int p = atomicAdd(&cur[d], 1);
                float nrm = dinv[s] * dinv[d];
                csr[p] = make_int2(s, __float_as_int(nrm));
            }
        }
    } else {
        reducebn_body(b - NB_FILL4, p2a, FOLD_BLOCKS, gamma1, beta1,
                      scale1, shift1, 1.0f / (float)n);
    }
}

// ---- reducebn2 + W2' prep + bias' partials (16 blocks, 8 channels each) ----
__global__ __launch_bounds__(256) void rbn2w2_kernel(
    const float* __restrict__ p2b,
    const float* __restrict__ gamma, const float* __restrict__ beta,
    const float* __restrict__ W2, __bf16* __restrict__ W2b,
    float* __restrict__ bias2p, int n) {
    __shared__ float l1[256], l2[256];
    __shared__ float ssc[8], ssh[8];
    int t = threadIdx.x;
    int blk = blockIdx.x;
    int cl = t & 7;
    int r0 = t >> 3;
    int c = blk * 8 + cl;
    float a1 = 0.f, a2 = 0.f;
    for (int r = r0; r < FOLD_BLOCKS; r += 32) {
        a1 += p2b[(size_t)r * 256 + c];
        a2 += p2b[(size_t)r * 256 + 128 + c];
    }
    l1[t] = a1; l2[t] = a2;
    __syncthreads();
    #pragma unroll
    for (int off = 16; off >= 1; off >>= 1) {
        if (r0 < off) {
            l1[t] += l1[t + off * 8];
            l2[t] += l2[t + off * 8];
        }
        __syncthreads();
    }
    if (t < 8) {
        int cc = blk * 8 + t;
        float inv_n = 1.0f / (float)n;
        float mean = l1[t] * inv_n;
        float var  = l2[t] * inv_n - mean * mean;
        float sc = gamma[cc] * rsqrtf(var + BN_EPS);
        float sh = beta[cc] - mean * sc;
        ssc[t] = sc;
        ssh[t] = sh;
    }
    __syncthreads();
    // W2' columns blk*8 .. blk*8+7 : W2'[j][k] = W2[j][k] * scale2[k]
    for (int idx = t; idx < 128 * 8; idx += 256) {
        int j = idx >> 3, kk = idx & 7;
        int k = blk * 8 + kk;
        W2b[j * CH + k] = (__bf16)(W2[j * CH + k] * ssc[kk]);
    }
    // bias' partial: bias2p[j] += sum_kk shift2[k] * W2[j][k]
    if (t < CH) {
        float acc = 0.f;
        #pragma unroll
        for (int kk = 0; kk < 8; ++kk)
            acc += ssh[kk] * W2[t * CH + blk * 8 + kk];
        atomicAdd(&bias2p[t], acc);
    }
}

// ---- MFMA GEMM 1: f32 A with BN1 transform ---------------------------------
#define GROWS 64
#define LDA 136

__global__ __launch_bounds__(256) void gemm_kernel(
    const float* __restrict__ A,
    const float* __restrict__ scale, const float* __restrict__ shift,
    const __bf16* __restrict__ Wb, __bf16* __restrict__ Hout, int n) {
    __shared__ __bf16 As[GROWS][LDA];
    int tid = threadIdx.x;
    int row0 = blockIdx.x * GROWS;

    #pragma unroll
    for (int p = 0; p < 8; ++p) {
        int idx = p * 256 + tid;
        int r = idx >> 5;
        int f4 = idx & 31;
        int c4 = f4 * 4;
        int row = row0 + r;
        f32x4 v = {0.f, 0.f, 0.f, 0.f};
        if (row < n) v = *((const f32x4*)A + ((size_t)row * 32 + f4));
        __bf16 u[4];
        #pragma unroll
        for (int j = 0; j < 4; ++j) {
            int ch = c4 + j;
            u[j] = (__bf16)(v[j] * scale[ch] + shift[ch]);
        }
        *(bf16x4*)&As[r][c4] = *(bf16x4*)u;
    }
    __syncthreads();

    int wv = tid >> 6;
    int lane = tid & 63;
    int m = lane & 15;
    int q = lane >> 4;
    int arow = wv * 16 + m;
    f32x4 acc[8] = {};
    #pragma unroll
    for (int kc = 0; kc < CH; kc += 32) {
        bf16x8 af = *(const bf16x8*)&As[arow][kc + q * 8];
        #pragma unroll
        for (int t = 0; t < 8; ++t) {
            bf16x8 bf = *(const bf16x8*)&Wb[(size_t)(t * 16 + m) * CH + kc + q * 8];
            acc[t] = __builtin_amdgcn_mfma_f32_16x16x32_bf16(af, bf, acc[t], 0, 0, 0);
        }
    }

    #pragma unroll
    for (int t = 0; t < 8; ++t) {
        #pragma unroll
        for (int r = 0; r < 4; ++r) {
            int row = row0 + wv * 16 + q * 4 + r;
            if (row < n) Hout[(size_t)row * CH + t * 16 + m] = (__bf16)acc[t][r];
        }
    }
}

// ---- MFMA GEMM 2'': aggH bf16 @ W2'^T + s*bias' + b2, relu, +x -> out f32 --
// LDS-transpose epilogue: acc -> Cs f32 tile -> vectorized coalesced stores.
#define LDC 132

__global__ __launch_bounds__(256) void gemm2_kernel(
    const __bf16* __restrict__ A, const __bf16* __restrict__ Wb,
    const float* __restrict__ bias2p, const float* __restrict__ s_arr,
    const float* __restrict__ b2, const float* __restrict__ x,
    float* __restrict__ out, int n) {
    __shared__ float Cs[GROWS][LDC];        // 33792 B; aliased as bf16 staging
    __bf16* As = (__bf16*)&Cs[0][0];        // [GROWS][LDA] bf16, 17408 B
    int tid = threadIdx.x;
    int row0 = blockIdx.x * GROWS;

    #pragma unroll
    for (int p = 0; p < 4; ++p) {
        int idx = p * 256 + tid;
        int r = idx >> 4;          // 64 rows, 16 slots of bf16x8
        int f8 = idx & 15;
        int c8 = f8 * 8;
        int row = row0 + r;
        bf16x8 v = {};
        if (row < n) v = *(const bf16x8*)&A[(size_t)row * CH + c8];
        *(bf16x8*)&As[r * LDA + c8] = v;
    }
    __syncthreads();

    int wv = tid >> 6;
    int lane = tid & 63;
    int m = lane & 15;
    int q = lane >> 4;
    int arow = wv * 16 + m;
    f32x4 acc[8] = {};
    #pragma unroll
    for (int kc = 0; kc < CH; kc += 32) {
        bf16x8 af = *(const bf16x8*)&As[arow * LDA + kc + q * 8];
        #pragma unroll
        for (int t = 0; t < 8; ++t) {
            bf16x8 bf = *(const bf16x8*)&Wb[(size_t)(t * 16 + m) * CH + kc + q * 8];
            acc[t] = __builtin_amdgcn_mfma_f32_16x16x32_bf16(af, bf, acc[t], 0, 0, 0);
        }
    }

    // transpose through LDS: scatter acc (fragment layout) -> row-major f32
    __syncthreads();   // all waves done reading As before overwrite
    #pragma unroll
    for (int t = 0; t < 8; ++t) {
        #pragma unroll
        for (int r = 0; r < 4; ++r)
            Cs[wv * 16 + q * 4 + r][t * 16 + m] = acc[t][r];
    }
    __syncthreads();

    // vectorized epilogue: 2048 f32x4 chunks, 8 per thread, coalesced
    #pragma unroll
    for (int k = 0; k < 8; ++k) {
        int cidx = k * 256 + tid;
        int r = cidx >> 5;
        int c4 = (cidx & 31) * 4;
        int row = row0 + r;
        if (row < n) {
            f32x4 a4 = *(f32x4*)&Cs[r][c4];
            float sv = s_arr[row];
            f32x4 bp = *(const f32x4*)&bias2p[c4];
            f32x4 bb = *(const f32x4*)&b2[c4];
            f32x4 xv = nt_load4(&x[(size_t)row * CH + c4]);
            f32x4 o;
            #pragma unroll
            for (int j = 0; j < 4; ++j)
                o[j] = fmaxf(a4[j] + sv * bp[j] + bb[j], 0.f) + xv[j];
            nt_store4(&out[(size_t)row * CH + c4], o);
        }
    }
}

// ---------------------------------------------------------------------------
// Gather core with batched pointer loads: lane (tid&15) fetches csr[e+lane]
// (one coalesced 128B load = up to 16 edge pointers per node-group), pointers
// distributed via __shfl. Returns sum of norms (for s[] = rowsum(A-hat)).
// ---------------------------------------------------------------------------
__device__ inline float agg_core(
    const __bf16* __restrict__ h, const int2* __restrict__ csr,
    const int* __restrict__ offs, const int* __restrict__ cnt,
    const float* __restrict__ dinv, int node, int c, float a[8]) {
    float di = dinv[node];
    float w0 = di * di;
    bf16x8 hv = *(const bf16x8*)&h[(size_t)node * CH + c];
    #pragma unroll
    for (int j = 0; j < 8; ++j) a[j] = bf2f(hv[j]) * w0;

    int e = offs[node];
    int end = e + cnt[node];
    int gl = threadIdx.x & 48;   // group base lane within wave
    int il = threadIdx.x & 15;   // lane within group
    float sn = 0.f;

    while (e < end) {
        int take = end - e;
        if (take > 16) take = 16;
        int2 pe = csr[e + (il < take ? il : take - 1)];
        int j = 0;
        for (; j + 4 <= take; j += 4) {
            int s0 = __shfl(pe.x, gl + j);
            int s1 = __shfl(pe.x, gl + j + 1);
            int s2 = __shfl(pe.x, gl + j + 2);
            int s3 = __shfl(pe.x, gl + j + 3);
            float n0 = __int_as_float(__shfl(pe.y, gl + j));
            float n1 = __int_as_float(__shfl(pe.y, gl + j + 1));
            float n2 = __int_as_float(__shfl(pe.y, gl + j + 2));
            float n3 = __int_as_float(__shfl(pe.y, gl + j + 3));
            bf16x8 v0 = *(const bf16x8*)&h[(size_t)s0 * CH + c];
            bf16x8 v1 = *(const bf16x8*)&h[(size_t)s1 * CH + c];
            bf16x8 v2 = *(const bf16x8*)&h[(size_t)s2 * CH + c];
            bf16x8 v3 = *(const bf16x8*)&h[(size_t)s3 * CH + c];
            sn += n0 + n1 + n2 + n3;
            #pragma unroll
            for (int k = 0; k < 8; ++k) {
                a[k] += bf2f(v0[k]) * n0;
                a[k] += bf2f(v1[k]) * n1;
                a[k] += bf2f(v2[k]) * n2;
                a[k] += bf2f(v3[k]) * n3;
            }
        }
        for (; j < take; ++j) {
            int s0 = __shfl(pe.x, gl + j);
            float n0 = __int_as_float(__shfl(pe.y, gl + j));
            bf16x8 v0 = *(const bf16x8*)&h[(size_t)s0 * CH + c];
            sn += n0;
            #pragma unroll
            for (int k = 0; k < 8; ++k) a[k] += bf2f(v0[k]) * n0;
        }
        e += take;
    }
    return sn;
}

// agg1: relu(a + b1) -> bf16 h2raw + s[] = rowsum(A-hat)
__global__ __launch_bounds__(256) void agg1_kernel(
    const __bf16* __restrict__ h, const int2* __restrict__ csr,
    const int* __restrict__ offs, const int* __restrict__ cnt,
    const float* __restrict__ dinv, const float* __restrict__ b1,
    __bf16* __restrict__ h2raw, float* __restrict__ s_arr, int n) {
    int tid = threadIdx.x;
    int node = blockIdx.x * 16 + (tid >> 4);
    if (node >= n) return;
    int c = (tid & 15) * 8;
    float a[8];
    float sn = agg_core(h, csr, offs, cnt, dinv, node, c, a);

    if ((tid & 15) == 0) {
        float di = dinv[node];
        s_arr[node] = di * di + sn;
    }

    __bf16 u[8];
    #pragma unroll
    for (int j = 0; j < 8; ++j) u[j] = (__bf16)fmaxf(a[j] + b1[c + j], 0.f);
    *(bf16x8*)&h2raw[(size_t)node * CH + c] = *(bf16x8*)u;
}

// agg2' + fused stats2: leading blocks gather h2raw -> aggH bf16;
// tail blocks stream h2raw -> per-channel sums into p2b (atomicAdd).
__global__ __launch_bounds__(256) void agg2s_kernel(
    const __bf16* __restrict__ h2, const int2* __restrict__ csr,
    const int* __restrict__ offs, const int* __restrict__ cnt,
    const float* __restrict__ dinv, __bf16* __restrict__ aggH,
    float* __restrict__ p2b, int n, int NB_AGG, int total16) {
    int b = blockIdx.x;
    int t = threadIdx.x;
    if (b < NB_AGG) {
        int node = b * 16 + (t >> 4);
        if (node >= n) return;
        int c = (t & 15) * 8;
        float a[8];
        agg_core(h2, csr, offs, cnt, dinv, node, c, a);
        __bf16 u[8];
        #pragma unroll
        for (int j = 0; j < 8; ++j) u[j] = (__bf16)a[j];
        *(bf16x8*)&aggH[(size_t)node * CH + c] = *(bf16x8*)u;
    } else {
        int sbid = b - NB_AGG;
        float s[8] = {}, q[8] = {};
        int gs = STATS2_GRID * 256;
        for (int i = sbid * 256 + t; i < total16; i += gs) {
            bf16x8 v = *(const bf16x8*)&h2[(size_t)i * 8];
            #pragma unroll
            for (int k = 0; k < 8; ++k) {
                float f = bf2f(v[k]);
                s[k] += f;
                q[k] += f * f;
            }
        }
        #pragma unroll
        for (int k = 0; k < 8; ++k) {
            s[k] += __shfl_xor(s[k], 16);
            q[k] += __shfl_xor(q[k], 16);
            s[k] += __shfl_xor(s[k], 32);
            q[k] += __shfl_xor(q[k], 32);
        }
        __shared__ float red[2][4][16][8];
        int w = t >> 6, l = t & 63;
        if (l < 16) {
            #pragma unroll
            for (int k = 0; k < 8; ++k) {
                red[0][w][l][k] = s[k];
                red[1][w][l][k] = q[k];
            }
        }
        __syncthreads();
        int half = t >> 7;
        int rem = t & 127;
        int g = rem >> 3;
        int k = rem & 7;
        float acc = red[half][0][g][k] + red[half][1][g][k]
                  + red[half][2][g][k] + red[half][3][g][k];
        atomicAdd(&p2b[(size_t)(sbid & 255) * 256 + half * 128 + g * 8 + k], acc);
    }
}

extern "C" void kernel_launch(void* const* d_in, const int* in_sizes, int n_in,
                              void* d_out, int out_size, void* d_ws, size_t ws_size,
                              hipStream_t stream) {
    const float* x      = (const float*)d_in[0];
    const int*   eidx   = (const int*)d_in[1];
    const float* W1     = (const float*)d_in[2];
    const float* b1     = (const float*)d_in[3];
    const float* W2     = (const float*)d_in[4];
    const float* b2     = (const float*)d_in[5];
    const float* gamma1 = (const float*)d_in[6];
    const float* beta1  = (const float*)d_in[7];
    const float* gamma2 = (const float*)d_in[8];
    const float* beta2  = (const float*)d_in[9];
    float* out = (float*)d_out;

    const int N = in_sizes[0] / CH;
    const int E = in_sizes[1] / 2;
    const int* src = eidx;
    const int* dst = eidx + E;

    const int NAGG = (N + 15) / 16;

    char* ws = (char*)d_ws;
    size_t off = 0;
    auto carve = [&](size_t bytes) { char* p = ws + off; off = (off + bytes + 1023) & ~(size_t)1023; return p; };
    // ---- zeroed region (one memset): cnt+cursor, bias2p, p2b ----
    int*    cnt      = (int*)carve((size_t)(N + 1) * 4);  // cnt[N] = scan cursor
    float*  bias2p   = (float*)carve(CH * 4);
    float*  p2b      = (float*)carve((size_t)FOLD_BLOCKS * 256 * 4);
    // ---- rest ----
    float*  dinv     = (float*)carve((size_t)N * 4);
    int*    offs     = (int*)carve((size_t)N * 4);
    int*    cur      = (int*)carve((size_t)N * 4);
    float*  s_arr    = (float*)carve((size_t)N * 4);
    float*  small    = (float*)carve(8 * CH * 4);
    float*  p2a      = (float*)carve((size_t)FOLD_BLOCKS * 256 * 4);
    float*  partials = (float*)carve((size_t)STATS_BLOCKS * 256 * 4);
    int2*   csr      = (int2*)carve((size_t)E * 8);
    __bf16* W1b      = (__bf16*)carve((size_t)CH * CH * 2);
    __bf16* W2b      = (__bf16*)carve((size_t)CH * CH * 2);  // holds W2' (prescaled)
    __bf16* h_bf     = (__bf16*)carve((size_t)N * CH * 2);   // gemm1 out; reused as aggH
    __bf16* h2raw    = (__bf16*)carve((size_t)N * CH * 2);   // relu(agg1+b1), bf16
    float* scale1 = small + 4 * CH;
    float* shift1 = small + 5 * CH;
    (void)ws_size; (void)n_in; (void)out_size;

    int* cursor = cnt + N;
    size_t zbytes = (size_t)((char*)p2b - (char*)cnt) + (size_t)FOLD_BLOCKS * 256 * 4;
    hipMemsetAsync(cnt, 0, zbytes, stream);

    const int NB_COUNT4 = (E + 1023) / 1024;
    const int NB_STATS  = STATS_BLOCKS;
    const int NB_WPREP  = (CH * CH + 255) / 256;
    const int NB_SCAN   = (N + 1023) / 1024;
    const int NB_DINV   = (N + 1023) / 1024;
    const int NB_FILL4  = (E + 1023) / 1024;
    const int NB_GEMM   = (N + GROWS - 1) / GROWS;

    // K1: count(4/thread, no-return atomics) + stats1(x)@2048 + W1 bf16 prep
    k1_kernel<<<NB_COUNT4 + NB_STATS + NB_WPREP, 256, 0, stream>>>(
        dst, cnt, E, x, partials, N * 32, W1, W1b, NB_COUNT4, NB_STATS);

    // K2: scan(atomic base; writes offs+cur) + dinv + fold1 (2048->256 rows)
    k2_kernel<<<NB_SCAN + NB_DINV + FOLD_BLOCKS, 256, 0, stream>>>(
        cnt, offs, cur, cursor, dinv, N, partials, p2a, NB_SCAN, NB_DINV);

    // fill CSR (4/thread, atomic cursor) + reducebn1 tail (16 blocks)
    fill_kernel<<<NB_FILL4 + 16, 256, 0, stream>>>(
        src, dst, cur, dinv, csr, E,
        p2a, gamma1, beta1, scale1, shift1, N, NB_FILL4);

    // gemm1: h = BN1(x) @ W1^T  (bf16 out)
    gemm_kernel<<<NB_GEMM, 256, 0, stream>>>(x, scale1, shift1, W1b, h_bf, N);

    // agg1: relu(A-hat h + b1) -> h2raw bf16 + s[] = rowsum(A-hat)
    agg1_kernel<<<NAGG, 256, 0, stream>>>(h_bf, csr, offs, cnt, dinv,
                                          b1, h2raw, s_arr, N);

    // agg2' (gather h2raw -> aggH bf16) + fused stats2 tail blocks
    agg2s_kernel<<<NAGG + STATS2_GRID, 256, 0, stream>>>(
        h2raw, csr, offs, cnt, dinv, h_bf, p2b, N, NAGG, N * 16);

    // reducebn2 + W2' prep + bias' accumulation
    rbn2w2_kernel<<<16, 256, 0, stream>>>(p2b, gamma2, beta2,
                                          W2, W2b, bias2p, N);

    // gemm2'': out = relu(aggH @ W2'^T + s*bias' + b2) + x  (f32, nt, LDS-transposed)
    gemm2_kernel<<<NB_GEMM, 256, 0, stream>>>(h_bf, W2b, bias2p, s_arr,
                                              b2, x, out, N);
}

// Round 10
// 346.445 us; speedup vs baseline: 1.1657x; 1.0886x over previous
//
#include <hip/hip_runtime.h>
#include <hip/hip_bf16.h>
#include <cstddef>

#define CH 128
#define BN_EPS 1e-5f
#define STATS_BLOCKS 2048
#define FOLD_BLOCKS 256
#define STATS2_GRID 2048

typedef __bf16 bf16x8 __attribute__((ext_vector_type(8)));
typedef __bf16 bf16x4 __attribute__((ext_vector_type(4)));
typedef float  f32x4  __attribute__((ext_vector_type(4)));

__device__ inline float bf2f(__bf16 b) { return (float)b; }

__device__ inline f32x4 nt_load4(const float* p) {
    return __builtin_nontemporal_load((const f32x4*)p);
}
__device__ inline void nt_store4(float* p, f32x4 v) {
    __builtin_nontemporal_store(v, (f32x4*)p);
}

// ---------------------------------------------------------------------------
// R16: (a) restore slot[] (R13's atomic-in-fill cost ~8us: R15 fill 53us,
// latency signature). (b) half-channel two-phase gather: blocks [0,G) do
// channels 0-63, [G,2G) do 64-127 (8 lanes/node, 32 nodes/block). Active
// random working set 25.6->12.8MB -> per-XCD L2 hit ~16%->~31% -> less LLC
// traffic (agg FETCH was 149MB of 256MB logical). csr read 2x (+8MB, cheap).
// Keep R13 commute + R15 LDS-transpose gemm2.
// ---------------------------------------------------------------------------

// ---- K1: count (4 edges/thread -> slot) + stats1 over x + wprep W1 ---------
__global__ __launch_bounds__(256) void k1_kernel(
    const int* __restrict__ dst, int* __restrict__ cnt, int* __restrict__ slot,
    int E, const float* __restrict__ x, float* __restrict__ partials, int total4,
    const float* __restrict__ W1, __bf16* __restrict__ W1b,
    int NB_COUNT4, int NB_STATS) {
    int b = blockIdx.x;
    if (b < NB_COUNT4) {
        int base = b * 1024 + threadIdx.x;
        #pragma unroll
        for (int j = 0; j < 4; ++j) {
            int e = base + j * 256;
            if (e < E) slot[e] = atomicAdd(&cnt[dst[e]], 1);
        }
    } else if (b < NB_COUNT4 + NB_STATS) {
        // per-channel sum & sumsq -> per-block partial row (sums||sumsq)
        int sbid = b - NB_COUNT4;
        int l = threadIdx.x & 31;
        int g = threadIdx.x >> 5;
        float4 s  = make_float4(0.f, 0.f, 0.f, 0.f);
        float4 s2 = make_float4(0.f, 0.f, 0.f, 0.f);
        int gid = sbid * 256 + threadIdx.x;
        int gs = NB_STATS * 256;
        const float4* in4 = (const float4*)x;

        auto accum = [&](float4 v) {
            s.x += v.x; s.y += v.y; s.z += v.z; s.w += v.w;
            s2.x += v.x * v.x; s2.y += v.y * v.y; s2.z += v.z * v.z; s2.w += v.w * v.w;
        };

        int i = gid;
        for (; i + 3 * gs < total4; i += 4 * gs) {
            float4 v0 = in4[i];
            float4 v1 = in4[i + gs];
            float4 v2 = in4[i + 2 * gs];
            float4 v3 = in4[i + 3 * gs];
            accum(v0); accum(v1); accum(v2); accum(v3);
        }
        for (; i < total4; i += gs) accum(in4[i]);

        __shared__ float4 ls[8][32], ls2[8][32];
        ls[g][l] = s; ls2[g][l] = s2;
        __syncthreads();
        if (g == 0) {
            #pragma unroll
            for (int k = 1; k < 8; ++k) {
                float4 a = ls[k][l], bb = ls2[k][l];
                s.x += a.x; s.y += a.y; s.z += a.z; s.w += a.w;
                s2.x += bb.x; s2.y += bb.y; s2.z += bb.z; s2.w += bb.w;
            }
            ((float4*)partials)[sbid * 64 + l]      = s;
            ((float4*)partials)[sbid * 64 + 32 + l] = s2;
        }
    } else {
        int i = (b - NB_COUNT4 - NB_STATS) * 256 + threadIdx.x;
        if (i < CH * CH) W1b[i] = (__bf16)W1[i];
    }
}

// ---- reduce partial rows + BN params (8 channels per block) ----------------
__device__ inline void reducebn_body(
    int blk, const float* __restrict__ partials, int R,
    const float* __restrict__ gamma, const float* __restrict__ beta,
    float* __restrict__ scale, float* __restrict__ shift, float inv_n) {
    __shared__ float l1[256], l2[256];
    int t = threadIdx.x;
    int cl = t & 7;
    int r0 = t >> 3;
    int c = blk * 8 + cl;
    float a1 = 0.f, a2 = 0.f;
    for (int r = r0; r < R; r += 32) {
        a1 += partials[(size_t)r * 256 + c];
        a2 += partials[(size_t)r * 256 + 128 + c];
    }
    l1[t] = a1; l2[t] = a2;
    __syncthreads();
    #pragma unroll
    for (int off = 16; off >= 1; off >>= 1) {
        if (r0 < off) {
            l1[t] += l1[t + off * 8];
            l2[t] += l2[t + off * 8];
        }
        __syncthreads();
    }
    if (t < 8) {
        float mean = l1[t] * inv_n;
        float var  = l2[t] * inv_n - mean * mean;  // biased
        float sc = gamma[c] * rsqrtf(var + BN_EPS);
        scale[c] = sc;
        shift[c] = beta[c] - mean * sc;
    }
}

// ---- K2: atomic-base scan + dinv + fold1 -----------------------------------
__global__ __launch_bounds__(256) void k2_kernel(
    const int* __restrict__ cnt, int* __restrict__ offs, int* __restrict__ cursor,
    float* __restrict__ dinv, int n,
    const float* __restrict__ partials, float* __restrict__ p2a,
    int NB_SCAN, int NB_DINV) {
    int b = blockIdx.x;
    int t = threadIdx.x;
    if (b < NB_SCAN) {
        __shared__ int sd[256];
        __shared__ int sbase;
        int base = b * 1024 + t * 4;
        int v[4];
        #pragma unroll
        for (int j = 0; j < 4; ++j) v[j] = (base + j < n) ? cnt[base + j] : 0;
        int s = v[0] + v[1] + v[2] + v[3];
        sd[t] = s;
        __syncthreads();
        for (int off = 1; off < 256; off <<= 1) {
            int xv = (t >= off) ? sd[t - off] : 0;
            __syncthreads();
            sd[t] += xv;
            __syncthreads();
        }
        if (t == 255) sbase = atomicAdd(cursor, sd[255]);
        __syncthreads();
        int run = sbase + sd[t] - s;
        #pragma unroll
        for (int j = 0; j < 4; ++j) {
            if (base + j < n) offs[base + j] = run;
            run += v[j];
        }
    } else if (b < NB_SCAN + NB_DINV) {
        int ib = (b - NB_SCAN) * 1024 + t * 4;
        #pragma unroll
        for (int j = 0; j < 4; ++j) {
            int i = ib + j;
            if (i < n) dinv[i] = rsqrtf((float)cnt[i] + 1.0f);  // +1 self loop
        }
    } else {
        // fold1: STATS_BLOCKS partial rows -> FOLD_BLOCKS rows
        int fb = b - NB_SCAN - NB_DINV;
        float acc = 0.f;
        for (int r = fb; r < STATS_BLOCKS; r += FOLD_BLOCKS)
            acc += partials[(size_t)r * 256 + t];
        p2a[(size_t)fb * 256 + t] = acc;
    }
}

// ---- fill CSR (4 edges/thread, slot-based, no atomics) + reducebn1 tail ----
__global__ __launch_bounds__(256) void fill_kernel(
    const int* __restrict__ src, const int* __restrict__ dst,
    const int* __restrict__ slot, const int* __restrict__ offs,
    const float* __restrict__ dinv, int2* __restrict__ csr, int E,
    const float* __restrict__ p2a,
    const float* __restrict__ gamma1, const float* __restrict__ beta1,
    float* __restrict__ scale1, float* __restrict__ shift1, int n,
    int NB_FILL4) {
    int b = blockIdx.x;
    if (b < NB_FILL4) {
        int base = b * 1024 + threadIdx.x;
        #pragma unroll
        for (int j = 0; j < 4; ++j) {
            int e = base + j * 256;
            if (e < E) {
                int s = src[e], d = dst[e];
                int p = offs[d] + slot[e];
                float nrm = dinv[s] * dinv[d];
                csr[p] = make_int2(s, __float_as_int(nrm));
            }
        }
    } else {
        reducebn_body(b - NB_FILL4, p2a, FOLD_BLOCKS, gamma1, beta1,
                      scale1, shift1, 1.0f / (float)n);
    }
}

// ---- reducebn2 + W2' prep + bias' partials (16 blocks, 8 channels each) ----
__global__ __launch_bounds__(256) void rbn2w2_kernel(
    const float* __restrict__ p2b,
    const float* __restrict__ gamma, const float* __restrict__ beta,
    const float* __restrict__ W2, __bf16* __restrict__ W2b,
    float* __restrict__ bias2p, int n) {
    __shared__ float l1[256], l2[256];
    __shared__ float ssc[8], ssh[8];
    int t = threadIdx.x;
    int blk = blockIdx.x;
    int cl = t & 7;
    int r0 = t >> 3;
    int c = blk * 8 + cl;
    float a1 = 0.f, a2 = 0.f;
    for (int r = r0; r < FOLD_BLOCKS; r += 32) {
        a1 += p2b[(size_t)r * 256 + c];
        a2 += p2b[(size_t)r * 256 + 128 + c];
    }
    l1[t] = a1; l2[t] = a2;
    __syncthreads();
    #pragma unroll
    for (int off = 16; off >= 1; off >>= 1) {
        if (r0 < off) {
            l1[t] += l1[t + off * 8];
            l2[t] += l2[t + off * 8];
        }
        __syncthreads();
    }
    if (t < 8) {
        int cc = blk * 8 + t;
        float inv_n = 1.0f / (float)n;
        float mean = l1[t] * inv_n;
        float var  = l2[t] * inv_n - mean * mean;
        float sc = gamma[cc] * rsqrtf(var + BN_EPS);
        float sh = beta[cc] - mean * sc;
        ssc[t] = sc;
        ssh[t] = sh;
    }
    __syncthreads();
    // W2' columns blk*8 .. blk*8+7 : W2'[j][k] = W2[j][k] * scale2[k]
    for (int idx = t; idx < 128 * 8; idx += 256) {
        int j = idx >> 3, kk = idx & 7;
        int k = blk * 8 + kk;
        W2b[j * CH + k] = (__bf16)(W2[j * CH + k] * ssc[kk]);
    }
    // bias' partial: bias2p[j] += sum_kk shift2[k] * W2[j][k]
    if (t < CH) {
        float acc = 0.f;
        #pragma unroll
        for (int kk = 0; kk < 8; ++kk)
            acc += ssh[kk] * W2[t * CH + blk * 8 + kk];
        atomicAdd(&bias2p[t], acc);
    }
}

// ---- MFMA GEMM 1: f32 A with BN1 transform ---------------------------------
#define GROWS 64
#define LDA 136

__global__ __launch_bounds__(256) void gemm_kernel(
    const float* __restrict__ A,
    const float* __restrict__ scale, const float* __restrict__ shift,
    const __bf16* __restrict__ Wb, __bf16* __restrict__ Hout, int n) {
    __shared__ __bf16 As[GROWS][LDA];
    int tid = threadIdx.x;
    int row0 = blockIdx.x * GROWS;

    #pragma unroll
    for (int p = 0; p < 8; ++p) {
        int idx = p * 256 + tid;
        int r = idx >> 5;
        int f4 = idx & 31;
        int c4 = f4 * 4;
        int row = row0 + r;
        f32x4 v = {0.f, 0.f, 0.f, 0.f};
        if (row < n) v = *((const f32x4*)A + ((size_t)row * 32 + f4));
        __bf16 u[4];
        #pragma unroll
        for (int j = 0; j < 4; ++j) {
            int ch = c4 + j;
            u[j] = (__bf16)(v[j] * scale[ch] + shift[ch]);
        }
        *(bf16x4*)&As[r][c4] = *(bf16x4*)u;
    }
    __syncthreads();

    int wv = tid >> 6;
    int lane = tid & 63;
    int m = lane & 15;
    int q = lane >> 4;
    int arow = wv * 16 + m;
    f32x4 acc[8] = {};
    #pragma unroll
    for (int kc = 0; kc < CH; kc += 32) {
        bf16x8 af = *(const bf16x8*)&As[arow][kc + q * 8];
        #pragma unroll
        for (int t = 0; t < 8; ++t) {
            bf16x8 bf = *(const bf16x8*)&Wb[(size_t)(t * 16 + m) * CH + kc + q * 8];
            acc[t] = __builtin_amdgcn_mfma_f32_16x16x32_bf16(af, bf, acc[t], 0, 0, 0);
        }
    }

    #pragma unroll
    for (int t = 0; t < 8; ++t) {
        #pragma unroll
        for (int r = 0; r < 4; ++r) {
            int row = row0 + wv * 16 + q * 4 + r;
            if (row < n) Hout[(size_t)row * CH + t * 16 + m] = (__bf16)acc[t][r];
        }
    }
}

// ---- MFMA GEMM 2'': aggH bf16 @ W2'^T + s*bias' + b2, relu, +x -> out f32 --
// LDS-transpose epilogue (R15): acc -> Cs f32 tile -> coalesced f32x4 stores.
#define LDC 132

__global__ __launch_bounds__(256) void gemm2_kernel(
    const __bf16* __restrict__ A, const __bf16* __restrict__ Wb,
    const float* __restrict__ bias2p, const float* __restrict__ s_arr,
    const float* __restrict__ b2, const float* __restrict__ x,
    float* __restrict__ out, int n) {
    __shared__ float Cs[GROWS][LDC];        // 33792 B; aliased as bf16 staging
    __bf16* As = (__bf16*)&Cs[0][0];        // [GROWS][LDA] bf16, 17408 B
    int tid = threadIdx.x;
    int row0 = blockIdx.x * GROWS;

    #pragma unroll
    for (int p = 0; p < 4; ++p) {
        int idx = p * 256 + tid;
        int r = idx >> 4;          // 64 rows, 16 slots of bf16x8
        int f8 = idx & 15;
        int c8 = f8 * 8;
        int row = row0 + r;
        bf16x8 v = {};
        if (row < n) v = *(const bf16x8*)&A[(size_t)row * CH + c8];
        *(bf16x8*)&As[r * LDA + c8] = v;
    }
    __syncthreads();

    int wv = tid >> 6;
    int lane = tid & 63;
    int m = lane & 15;
    int q = lane >> 4;
    int arow = wv * 16 + m;
    f32x4 acc[8] = {};
    #pragma unroll
    for (int kc = 0; kc < CH; kc += 32) {
        bf16x8 af = *(const bf16x8*)&As[arow * LDA + kc + q * 8];
        #pragma unroll
        for (int t = 0; t < 8; ++t) {
            bf16x8 bf = *(const bf16x8*)&Wb[(size_t)(t * 16 + m) * CH + kc + q * 8];
            acc[t] = __builtin_amdgcn_mfma_f32_16x16x32_bf16(af, bf, acc[t], 0, 0, 0);
        }
    }

    // transpose through LDS: scatter acc (fragment layout) -> row-major f32
    __syncthreads();   // all waves done reading As before overwrite
    #pragma unroll
    for (int t = 0; t < 8; ++t) {
        #pragma unroll
        for (int r = 0; r < 4; ++r)
            Cs[wv * 16 + q * 4 + r][t * 16 + m] = acc[t][r];
    }
    __syncthreads();

    // vectorized epilogue: 2048 f32x4 chunks, 8 per thread, coalesced
    #pragma unroll
    for (int k = 0; k < 8; ++k) {
        int cidx = k * 256 + tid;
        int r = cidx >> 5;
        int c4 = (cidx & 31) * 4;
        int row = row0 + r;
        if (row < n) {
            f32x4 a4 = *(f32x4*)&Cs[r][c4];
            float sv = s_arr[row];
            f32x4 bp = *(const f32x4*)&bias2p[c4];
            f32x4 bb = *(const f32x4*)&b2[c4];
            f32x4 xv = nt_load4(&x[(size_t)row * CH + c4]);
            f32x4 o;
            #pragma unroll
            for (int j = 0; j < 4; ++j)
                o[j] = fmaxf(a4[j] + sv * bp[j] + bb[j], 0.f) + xv[j];
            nt_store4(&out[(size_t)row * CH + c4], o);
        }
    }
}

// ---------------------------------------------------------------------------
// Half-channel gather core: 8 lanes/node, 8 ch/lane (one 64-ch half).
// lane (tid&7) fetches csr[e+lane] (coalesced 64B = 8 edge pointers),
// distributed via __shfl. Returns sum of norms.
// ---------------------------------------------------------------------------
__device__ inline float agg_core8(
    const __bf16* __restrict__ h, const int2* __restrict__ csr,
    const int* __restrict__ offs, const int* __restrict__ cnt,
    const float* __restrict__ dinv, int node, int c, float a[8]) {
    float di = dinv[node];
    float w0 = di * di;
    bf16x8 hv = *(const bf16x8*)&h[(size_t)node * CH + c];
    #pragma unroll
    for (int j = 0; j < 8; ++j) a[j] = bf2f(hv[j]) * w0;

    int e = offs[node];
    int end = e + cnt[node];
    int gl = threadIdx.x & 56;   // group base lane within wave (8-lane groups)
    int il = threadIdx.x & 7;    // lane within group
    float sn = 0.f;

    while (e < end) {
        int take = end - e;
        if (take > 8) take = 8;
        int2 pe = csr[e + (il < take ? il : take - 1)];
        int j = 0;
        for (; j + 4 <= take; j += 4) {
            int s0 = __shfl(pe.x, gl + j);
            int s1 = __shfl(pe.x, gl + j + 1);
            int s2 = __shfl(pe.x, gl + j + 2);
            int s3 = __shfl(pe.x, gl + j + 3);
            float n0 = __int_as_float(__shfl(pe.y, gl + j));
            float n1 = __int_as_float(__shfl(pe.y, gl + j + 1));
            float n2 = __int_as_float(__shfl(pe.y, gl + j + 2));
            float n3 = __int_as_float(__shfl(pe.y, gl + j + 3));
            bf16x8 v0 = *(const bf16x8*)&h[(size_t)s0 * CH + c];
            bf16x8 v1 = *(const bf16x8*)&h[(size_t)s1 * CH + c];
            bf16x8 v2 = *(const bf16x8*)&h[(size_t)s2 * CH + c];
            bf16x8 v3 = *(const bf16x8*)&h[(size_t)s3 * CH + c];
            sn += n0 + n1 + n2 + n3;
            #pragma unroll
            for (int k = 0; k < 8; ++k) {
                a[k] += bf2f(v0[k]) * n0;
                a[k] += bf2f(v1[k]) * n1;
                a[k] += bf2f(v2[k]) * n2;
                a[k] += bf2f(v3[k]) * n3;
            }
        }
        for (; j < take; ++j) {
            int s0 = __shfl(pe.x, gl + j);
            float n0 = __int_as_float(__shfl(pe.y, gl + j));
            bf16x8 v0 = *(const bf16x8*)&h[(size_t)s0 * CH + c];
            sn += n0;
            #pragma unroll
            for (int k = 0; k < 8; ++k) a[k] += bf2f(v0[k]) * n0;
        }
        e += take;
    }
    return sn;
}

// agg1: relu(a + b1) -> bf16 h2raw (half-channel two-phase) + s_arr
__global__ __launch_bounds__(256) void agg1_kernel(
    const __bf16* __restrict__ h, const int2* __restrict__ csr,
    const int* __restrict__ offs, const int* __restrict__ cnt,
    const float* __restrict__ dinv, const float* __restrict__ b1,
    __bf16* __restrict__ h2raw, float* __restrict__ s_arr, int n, int G) {
    int b = blockIdx.x;
    int half = (b >= G) ? 1 : 0;
    int bl = b - half * G;
    int tid = threadIdx.x;
    int node = bl * 32 + (tid >> 3);
    if (node >= n) return;
    int c = (tid & 7) * 8 + half * 64;
    float a[8];
    float sn = agg_core8(h, csr, offs, cnt, dinv, node, c, a);

    if (half == 0 && (tid & 7) == 0) {
        float di = dinv[node];
        s_arr[node] = di * di + sn;
    }

    __bf16 u[8];
    #pragma unroll
    for (int j = 0; j < 8; ++j) u[j] = (__bf16)fmaxf(a[j] + b1[c + j], 0.f);
    *(bf16x8*)&h2raw[(size_t)node * CH + c] = *(bf16x8*)u;
}

// agg2' (half-channel two-phase gather h2raw -> aggH bf16) + stats2 tail
__global__ __launch_bounds__(256) void agg2s_kernel(
    const __bf16* __restrict__ h2, const int2* __restrict__ csr,
    const int* __restrict__ offs, const int* __restrict__ cnt,
    const float* __restrict__ dinv, __bf16* __restrict__ aggH,
    float* __restrict__ p2b, int n, int G, int total16) {
    int b = blockIdx.x;
    int t = threadIdx.x;
    if (b < 2 * G) {
        int half = (b >= G) ? 1 : 0;
        int bl = b - half * G;
        int node = bl * 32 + (t >> 3);
        if (node >= n) return;
        int c = (t & 7) * 8 + half * 64;
        float a[8];
        agg_core8(h2, csr, offs, cnt, dinv, node, c, a);
        __bf16 u[8];
        #pragma unroll
        for (int j = 0; j < 8; ++j) u[j] = (__bf16)a[j];
        *(bf16x8*)&aggH[(size_t)node * CH + c] = *(bf16x8*)u;
    } else {
        int sbid = b - 2 * G;
        float s[8] = {}, q[8] = {};
        int gs = STATS2_GRID * 256;
        for (int i = sbid * 256 + t; i < total16; i += gs) {
            bf16x8 v = *(const bf16x8*)&h2[(size_t)i * 8];
            #pragma unroll
            for (int k = 0; k < 8; ++k) {
                float f = bf2f(v[k]);
                s[k] += f;
                q[k] += f * f;
            }
        }
        #pragma unroll
        for (int k = 0; k < 8; ++k) {
            s[k] += __shfl_xor(s[k], 16);
            q[k] += __shfl_xor(q[k], 16);
            s[k] += __shfl_xor(s[k], 32);
            q[k] += __shfl_xor(q[k], 32);
        }
        __shared__ float red[2][4][16][8];
        int w = t >> 6, l = t & 63;
        if (l < 16) {
            #pragma unroll
            for (int k = 0; k < 8; ++k) {
                red[0][w][l][k] = s[k];
                red[1][w][l][k] = q[k];
            }
        }
        __syncthreads();
        int half = t >> 7;
        int rem = t & 127;
        int g = rem >> 3;
        int k = rem & 7;
        float acc = red[half][0][g][k] + red[half][1][g][k]
                  + red[half][2][g][k] + red[half][3][g][k];
        atomicAdd(&p2b[(size_t)(sbid & 255) * 256 + half * 128 + g * 8 + k], acc);
    }
}

extern "C" void kernel_launch(void* const* d_in, const int* in_sizes, int n_in,
                              void* d_out, int out_size, void* d_ws, size_t ws_size,
                              hipStream_t stream) {
    const float* x      = (const float*)d_in[0];
    const int*   eidx   = (const int*)d_in[1];
    const float* W1     = (const float*)d_in[2];
    const float* b1     = (const float*)d_in[3];
    const float* W2     = (const float*)d_in[4];
    const float* b2     = (const float*)d_in[5];
    const float* gamma1 = (const float*)d_in[6];
    const float* beta1  = (const float*)d_in[7];
    const float* gamma2 = (const float*)d_in[8];
    const float* beta2  = (const float*)d_in[9];
    float* out = (float*)d_out;

    const int N = in_sizes[0] / CH;
    const int E = in_sizes[1] / 2;
    const int* src = eidx;
    const int* dst = eidx + E;

    const int G32 = (N + 31) / 32;   // blocks per channel-half in the gathers

    char* ws = (char*)d_ws;
    size_t off = 0;
    auto carve = [&](size_t bytes) { char* p = ws + off; off = (off + bytes + 1023) & ~(size_t)1023; return p; };
    // ---- zeroed region (one memset): cnt+cursor, bias2p, p2b ----
    int*    cnt      = (int*)carve((size_t)(N + 1) * 4);  // cnt[N] = scan cursor
    float*  bias2p   = (float*)carve(CH * 4);
    float*  p2b      = (float*)carve((size_t)FOLD_BLOCKS * 256 * 4);
    // ---- rest ----
    float*  dinv     = (float*)carve((size_t)N * 4);
    int*    offs     = (int*)carve((size_t)N * 4);
    int*    slot     = (int*)carve((size_t)E * 4);
    float*  s_arr    = (float*)carve((size_t)N * 4);
    float*  small    = (float*)carve(8 * CH * 4);
    float*  p2a      = (float*)carve((size_t)FOLD_BLOCKS * 256 * 4);
    float*  partials = (float*)carve((size_t)STATS_BLOCKS * 256 * 4);
    int2*   csr      = (int2*)carve((size_t)E * 8);
    __bf16* W1b      = (__bf16*)carve((size_t)CH * CH * 2);
    __bf16* W2b      = (__bf16*)carve((size_t)CH * CH * 2);  // holds W2' (prescaled)
    __bf16* h_bf     = (__bf16*)carve((size_t)N * CH * 2);   // gemm1 out; reused as aggH
    __bf16* h2raw    = (__bf16*)carve((size_t)N * CH * 2);   // relu(agg1+b1), bf16
    float* scale1 = small + 4 * CH;
    float* shift1 = small + 5 * CH;
    (void)ws_size; (void)n_in; (void)out_size;

    int* cursor = cnt + N;
    size_t zbytes = (size_t)((char*)p2b - (char*)cnt) + (size_t)FOLD_BLOCKS * 256 * 4;
    hipMemsetAsync(cnt, 0, zbytes, stream);

    const int NB_COUNT4 = (E + 1023) / 1024;
    const int NB_STATS  = STATS_BLOCKS;
    const int NB_WPREP  = (CH * CH + 255) / 256;
    const int NB_SCAN   = (N + 1023) / 1024;
    const int NB_DINV   = (N + 1023) / 1024;
    const int NB_FILL4  = (E + 1023) / 1024;
    const int NB_GEMM   = (N + GROWS - 1) / GROWS;

    // K1: count(4/thread -> slot) + stats1(x)@2048 + W1 bf16 prep
    k1_kernel<<<NB_COUNT4 + NB_STATS + NB_WPREP, 256, 0, stream>>>(
        dst, cnt, slot, E, x, partials, N * 32, W1, W1b, NB_COUNT4, NB_STATS);

    // K2: scan(atomic base) + dinv + fold1 (2048 -> 256 rows)
    k2_kernel<<<NB_SCAN + NB_DINV + FOLD_BLOCKS, 256, 0, stream>>>(
        cnt, offs, cursor, dinv, N, partials, p2a, NB_SCAN, NB_DINV);

    // fill CSR (4/thread, slot-based) + reducebn1 tail (16 blocks)
    fill_kernel<<<NB_FILL4 + 16, 256, 0, stream>>>(
        src, dst, slot, offs, dinv, csr, E,
        p2a, gamma1, beta1, scale1, shift1, N, NB_FILL4);

    // gemm1: h = BN1(x) @ W1^T  (bf16 out)
    gemm_kernel<<<NB_GEMM, 256, 0, stream>>>(x, scale1, shift1, W1b, h_bf, N);

    // agg1: relu(A-hat h + b1) -> h2raw bf16 (half-channel 2-phase) + s_arr
    agg1_kernel<<<2 * G32, 256, 0, stream>>>(h_bf, csr, offs, cnt, dinv,
                                             b1, h2raw, s_arr, N, G32);

    // agg2' (half-channel 2-phase gather -> aggH) + fused stats2 tail
    agg2s_kernel<<<2 * G32 + STATS2_GRID, 256, 0, stream>>>(
        h2raw, csr, offs, cnt, dinv, h_bf, p2b, N, G32, N * 16);

    // reducebn2 + W2' prep + bias' accumulation
    rbn2w2_kernel<<<16, 256, 0, stream>>>(p2b, gamma2, beta2,
                                          W2, W2b, bias2p, N);

    // gemm2'': out = relu(aggH @ W2'^T + s*bias' + b2) + x  (f32, nt, LDS-transposed)
    gemm2_kernel<<<NB_GEMM, 256, 0, stream>>>(h_bf, W2b, bias2p, s_arr,
                                              b2, x, out, N);
}